// Round 4
// baseline (154.997 us; speedup 1.0000x reference)
//
#include <hip/hip_runtime.h>
#include <hip/hip_bf16.h>
#include <math.h>

#define NTOK 8192     // B*L
#define DIM  1024     // D
#define VDIM 32       // V
#define KCODES 4096   // K

typedef __attribute__((ext_vector_type(8))) short short8;
typedef __attribute__((ext_vector_type(4))) float f32x4;

// MFMA16(A,B,C): D[row=4q+r <- A-frag row][col=m <- B's n-dim]; A-frag lane(q,m)
// holds A[m][k=q*8+j], B-frag lane(q,m) holds B[n=m][k=q*8+j]. (verified R2/R3)
#define MFMA16(A,B,C) __builtin_amdgcn_mfma_f32_16x16x32_bf16(A, B, C, 0, 0, 0)

__device__ __forceinline__ unsigned short f2bf(float x) {
    unsigned u = __builtin_bit_cast(unsigned, x);
    u += 0x7FFF + ((u >> 16) & 1);              // RTNE (finite inputs only)
    return (unsigned short)(u >> 16);
}
__device__ __forceinline__ float bf2f(unsigned short b) {
    unsigned u = ((unsigned)b) << 16;
    return __builtin_bit_cast(float, u);
}

struct U4 { unsigned x, y, z, w; };

// split 8 fp32 -> bf16 hi/lo fragments (element j of frag = p[j])
__device__ __forceinline__ void split8(const float* p, short8* H, short8* L) {
    unsigned hh[4], ll[4];
    #pragma unroll
    for (int i = 0; i < 4; ++i) {
        unsigned short a = f2bf(p[2 * i]);
        unsigned short b = f2bf(p[2 * i + 1]);
        hh[i] = (unsigned)a | ((unsigned)b << 16);
        unsigned short la = f2bf(p[2 * i] - bf2f(a));
        unsigned short lb = f2bf(p[2 * i + 1] - bf2f(b));
        ll[i] = (unsigned)la | ((unsigned)lb << 16);
    }
    U4 uh = {hh[0], hh[1], hh[2], hh[3]};
    U4 ul = {ll[0], ll[1], ll[2], ll[3]};
    *H = __builtin_bit_cast(short8, uh);
    *L = __builtin_bit_cast(short8, ul);
}

// pack 8 fp32 -> bf16 hi-only fragment
__device__ __forceinline__ short8 pack8hi(const float* p) {
    unsigned hh[4];
    #pragma unroll
    for (int i = 0; i < 4; ++i) {
        unsigned short a = f2bf(p[2 * i]);
        unsigned short b = f2bf(p[2 * i + 1]);
        hh[i] = (unsigned)a | ((unsigned)b << 16);
    }
    U4 uh = {hh[0], hh[1], hh[2], hh[3]};
    return __builtin_bit_cast(short8, uh);
}

// ---------------------------------------------------------------------------
// ws layout (u16 units)
// ---------------------------------------------------------------------------
#define OFS_E_HI   0          // E  [4096][32]
#define OFS_E_LO   131072
#define OFS_ET_HI  262144     // Et [32][4096]
#define OFS_ET_LO  393216
#define OFS_WP_HI  524288     // Wp [32][1024]
#define OFS_WP_LO  557056
#define OFS_WPI_HI 589824     // Wpi [1024][32]
#define OFS_WPI_LO 622592

// ---------------------------------------------------------------------------
// k_prep: normalize emb -> E hi/lo (row-major) + Et hi/lo (coalesced via LDS
// transpose); split Wp/Wpi into bf16 hi/lo; vq_loss = 0.
// ---------------------------------------------------------------------------
__global__ __launch_bounds__(256) void k_prep(const float* __restrict__ emb,
                                              const float* __restrict__ Wp,
                                              const float* __restrict__ Wpi,
                                              unsigned short* __restrict__ W,
                                              float* __restrict__ loss_out) {
    __shared__ __align__(16) unsigned short Th[32][72];
    __shared__ __align__(16) unsigned short Tl[32][72];
    int bid = blockIdx.x, tid = threadIdx.x;
    if (bid < 64) {                       // 64 codes per block
        int cb = bid * 64;
        int c = tid >> 2, s = tid & 3;    // code-local, v-quarter
        const float* src = emb + (size_t)(cb + c) * VDIM + s * 8;
        float4 a = *(const float4*)src;
        float4 b = *(const float4*)(src + 4);
        float ps = a.x*a.x + a.y*a.y + a.z*a.z + a.w*a.w
                 + b.x*b.x + b.y*b.y + b.z*b.z + b.w*b.w;
        ps += __shfl_xor(ps, 1);
        ps += __shfl_xor(ps, 2);
        float inv = 1.0f / sqrtf(ps);
        float vals[8] = {a.x*inv, a.y*inv, a.z*inv, a.w*inv,
                         b.x*inv, b.y*inv, b.z*inv, b.w*inv};
        short8 H, L;
        split8(vals, &H, &L);
        *(short8*)(W + OFS_E_HI + (size_t)(cb + c) * VDIM + s * 8) = H;
        *(short8*)(W + OFS_E_LO + (size_t)(cb + c) * VDIM + s * 8) = L;
        #pragma unroll
        for (int j = 0; j < 8; ++j) {
            unsigned short hb = f2bf(vals[j]);
            Th[s * 8 + j][c] = hb;
            Tl[s * 8 + j][c] = f2bf(vals[j] - bf2f(hb));
        }
        __syncthreads();
        int row = tid >> 3, seg = tid & 7;
        *(short8*)(W + OFS_ET_HI + (size_t)row * KCODES + cb + seg * 8) =
            *(const short8*)&Th[row][seg * 8];
        *(short8*)(W + OFS_ET_LO + (size_t)row * KCODES + cb + seg * 8) =
            *(const short8*)&Tl[row][seg * 8];
        if (bid == 0 && tid == 0) loss_out[0] = 0.0f;
    } else if (bid < 80) {                // Wp split: 16 blocks x 2048
        int i0 = (bid - 64) * 2048 + tid * 8;
        float4 a = *(const float4*)(Wp + i0);
        float4 b = *(const float4*)(Wp + i0 + 4);
        float vals[8] = {a.x, a.y, a.z, a.w, b.x, b.y, b.z, b.w};
        short8 H, L;
        split8(vals, &H, &L);
        *(short8*)(W + OFS_WP_HI + i0) = H;
        *(short8*)(W + OFS_WP_LO + i0) = L;
    } else {                              // Wpi split: 16 blocks x 2048
        int i0 = (bid - 80) * 2048 + tid * 8;
        float4 a = *(const float4*)(Wpi + i0);
        float4 b = *(const float4*)(Wpi + i0 + 4);
        float vals[8] = {a.x, a.y, a.z, a.w, b.x, b.y, b.z, b.w};
        short8 H, L;
        split8(vals, &H, &L);
        *(short8*)(W + OFS_WPI_HI + i0) = H;
        *(short8*)(W + OFS_WPI_LO + i0) = L;
    }
}

// ---------------------------------------------------------------------------
// k_fused: proj+normalize -> scores -> softmax/argmax -> P@E^T -> out-GEMM.
// 512 blocks x 512 threads (8 waves), 16 tokens/block -> 2 blocks/CU resident.
// Transposed GEMMs + sigma-permuted A-rows: softmax output feeds PV in-register.
// Phase-2 chunk loop register-double-buffers the E/Et fragments.
// ---------------------------------------------------------------------------
__global__ __launch_bounds__(512) void k_fused(const float* __restrict__ h,
                                               const float* __restrict__ mask,
                                               const unsigned short* __restrict__ W,
                                               const float* __restrict__ bp,
                                               const float* __restrict__ bpi,
                                               float* __restrict__ out,
                                               float* __restrict__ code_out) {
    __shared__ __align__(16) float red2[8][16][36];          // 18.4 KB merge buffer
    __shared__ __align__(16) unsigned short hpB_hi[16][40];
    __shared__ __align__(16) unsigned short hpB_lo[16][40];
    __shared__ __align__(16) unsigned short hvB_hi[16][40];
    __shared__ __align__(16) unsigned short hvB_lo[16][40];
    __shared__ float lred[8][16];
    __shared__ float amred[8][16];
    __shared__ int   aired[8][16];
    __shared__ float invl[16];

    const unsigned short* E_hi   = W + OFS_E_HI;
    const unsigned short* E_lo   = W + OFS_E_LO;
    const unsigned short* Et_hi  = W + OFS_ET_HI;
    const unsigned short* Et_lo  = W + OFS_ET_LO;
    const unsigned short* Wp_hi  = W + OFS_WP_HI;
    const unsigned short* Wp_lo  = W + OFS_WP_LO;
    const unsigned short* Wpi_hi = W + OFS_WPI_HI;
    const unsigned short* Wpi_lo = W + OFS_WPI_LO;

    int tid = threadIdx.x;
    int w = tid >> 6;                        // wave 0..7
    int l = tid & 63;
    int q = l >> 4, m = l & 15;
    int tok0 = blockIdx.x * 16;
    int sig = ((m & 12) << 1) | (m & 3);     // sigma(m) = 8*(m>>2) + (m&3)
    const f32x4 zero4 = {0.f, 0.f, 0.f, 0.f};

    // ================= Phase 1: hp = h @ Wp^T + bp, L2-normalize =============
    {
        f32x4 acc0 = zero4, acc1 = zero4;     // v-tiles 0..15, 16..31
        const float* hb = h + (size_t)(tok0 + m) * DIM + w * 128 + q * 8;
        const unsigned short* w0h = Wp_hi + (size_t)m * DIM + w * 128 + q * 8;
        const unsigned short* w0l = Wp_lo + (size_t)m * DIM + w * 128 + q * 8;
        const unsigned short* w1h = w0h + (size_t)16 * DIM;
        const unsigned short* w1l = w0l + (size_t)16 * DIM;
        #pragma unroll
        for (int c = 0; c < 4; ++c) {
            float4 a = *(const float4*)(hb + c * 32);
            float4 b = *(const float4*)(hb + c * 32 + 4);
            float va[8] = {a.x, a.y, a.z, a.w, b.x, b.y, b.z, b.w};
            short8 Bh, Bl;
            split8(va, &Bh, &Bl);
            short8 A0h = *(const short8*)(w0h + c * 32);
            short8 A0l = *(const short8*)(w0l + c * 32);
            short8 A1h = *(const short8*)(w1h + c * 32);
            short8 A1l = *(const short8*)(w1l + c * 32);
            acc0 = MFMA16(A0l, Bl, acc0); acc0 = MFMA16(A0l, Bh, acc0);
            acc0 = MFMA16(A0h, Bl, acc0); acc0 = MFMA16(A0h, Bh, acc0);
            acc1 = MFMA16(A1l, Bl, acc1); acc1 = MFMA16(A1l, Bh, acc1);
            acc1 = MFMA16(A1h, Bl, acc1); acc1 = MFMA16(A1h, Bh, acc1);
        }
        // lane(q,m) reg r -> hp_partial[v = 4q+r (+16)][token m]
        *(f32x4*)&red2[w][m][4 * q]      = acc0;
        *(f32x4*)&red2[w][m][16 + 4 * q] = acc1;
    }
    __syncthreads();
    {   // merge + bias + normalize -> hpB (bf16 hi/lo in LDS)
        int t = tid >> 5, v = tid & 31;
        float s = bp[v];
        #pragma unroll
        for (int j = 0; j < 8; ++j) s += red2[j][t][v];
        float sq = s * s;
        #pragma unroll
        for (int off = 1; off < 32; off <<= 1) sq += __shfl_xor(sq, off);
        float nv = s * (1.0f / sqrtf(sq));
        unsigned short hb = f2bf(nv);
        hpB_hi[t][v] = hb;
        hpB_lo[t][v] = f2bf(nv - bf2f(hb));
    }
    __syncthreads();

    // ================= Phase 2: scores -> softmax -> P@E^T ===================
    short8 hph = *(const short8*)&hpB_hi[m][q * 8];
    short8 hpl = *(const short8*)&hpB_lo[m][q * 8];

    f32x4 hv0 = zero4, hv1 = zero4;
    float ls = 0.f, am = -1e30f;
    int ai = 0;

    int cb = w * 512;                        // wave's 512-code slice
    size_t e0 = (size_t)(cb + sig) * VDIM + q * 8;
    size_t t0 = (size_t)sig * KCODES + cb + q * 8;
    short8 E0h = *(const short8*)(E_hi + e0);
    short8 E0l = *(const short8*)(E_lo + e0);
    short8 E1h = *(const short8*)(E_hi + e0 + 4 * VDIM);
    short8 E1l = *(const short8*)(E_lo + e0 + 4 * VDIM);
    short8 T0h = *(const short8*)(Et_hi + t0);
    short8 T0l = *(const short8*)(Et_lo + t0);
    short8 T1h = *(const short8*)(Et_hi + t0 + (size_t)4 * KCODES);
    short8 T1l = *(const short8*)(Et_lo + t0 + (size_t)4 * KCODES);

    #pragma unroll 2
    for (int c = 0; c < 16; ++c) {
        // prefetch next chunk (final iter reads in-bounds-unused ws bytes)
        size_t ne = e0 + 1024, nt = t0 + 32;
        short8 nE0h = *(const short8*)(E_hi + ne);
        short8 nE0l = *(const short8*)(E_lo + ne);
        short8 nE1h = *(const short8*)(E_hi + ne + 4 * VDIM);
        short8 nE1l = *(const short8*)(E_lo + ne + 4 * VDIM);
        short8 nT0h = *(const short8*)(Et_hi + nt);
        short8 nT0l = *(const short8*)(Et_lo + nt);
        short8 nT1h = *(const short8*)(Et_hi + nt + (size_t)4 * KCODES);
        short8 nT1l = *(const short8*)(Et_lo + nt + (size_t)4 * KCODES);

        // scores (4-product split fp32: argmax-grade)
        f32x4 s0 = MFMA16(E0l, hpl, zero4);
        s0 = MFMA16(E0l, hph, s0);
        s0 = MFMA16(E0h, hpl, s0);
        s0 = MFMA16(E0h, hph, s0);
        f32x4 s1 = MFMA16(E1l, hpl, zero4);
        s1 = MFMA16(E1l, hph, s1);
        s1 = MFMA16(E1h, hpl, s1);
        s1 = MFMA16(E1h, hph, s1);

        float p[8];
        int cbase = cb + 8 * q;              // lane's codes: cbase+j, j=0..7
        #pragma unroll
        for (int r = 0; r < 4; ++r) {
            float sv = s0[r];
            if (sv > am) { am = sv; ai = cbase + r; }
            p[r] = __expf(2.0f * sv);
            sv = s1[r];
            if (sv > am) { am = sv; ai = cbase + 4 + r; }
            p[4 + r] = __expf(2.0f * sv);
        }
        ls += ((p[0] + p[1]) + (p[2] + p[3])) + ((p[4] + p[5]) + (p[6] + p[7]));
        short8 Ph = pack8hi(p);
        // PV (P hi-only; keep Et lo term)
        hv0 = MFMA16(T0l, Ph, hv0);
        hv0 = MFMA16(T0h, Ph, hv0);
        hv1 = MFMA16(T1l, Ph, hv1);
        hv1 = MFMA16(T1h, Ph, hv1);

        E0h = nE0h; E0l = nE0l; E1h = nE1h; E1l = nE1l;
        T0h = nT0h; T0l = nT0l; T1h = nT1h; T1l = nT1l;
        e0 = ne; t0 = nt; cb += 32;
    }

    // reduce l/argmax across q (lane bits 4,5 share token column m)
    #pragma unroll
    for (int off = 16; off <= 32; off <<= 1) {
        ls += __shfl_xor(ls, off);
        float a2 = __shfl_xor(am, off);
        int   i2 = __shfl_xor(ai, off);
        if (a2 > am || (a2 == am && i2 < ai)) { am = a2; ai = i2; }
    }
    if (q == 0) {            // l == m
        lred[w][m] = ls; amred[w][m] = am; aired[w][m] = ai;
    }
    // hv partials: lane(q,m) reg r -> hv[v = 8q+r (+4)][token m]
    *(f32x4*)&red2[w][m][8 * q]     = hv0;
    *(f32x4*)&red2[w][m][8 * q + 4] = hv1;
    __syncthreads();

    if (tid < 16) {
        float L = 0.f, A = -1e30f;
        int I = 0x7fffffff;
        #pragma unroll
        for (int j = 0; j < 8; ++j) {
            L += lred[j][tid];
            float a2 = amred[j][tid];
            int   i2 = aired[j][tid];
            if (a2 > A || (a2 == A && i2 < I)) { A = a2; I = i2; }
        }
        bool on = (mask[tok0 + tid] == 1.0f);
        code_out[tok0 + tid] = on ? (float)I : 0.0f;
        invl[tid] = on ? (1.0f / L) : 0.0f;
    }
    float xsum;
    {
        int t = tid >> 5, v = tid & 31;
        float x = 0.f;
        #pragma unroll
        for (int j = 0; j < 8; ++j) x += red2[j][t][v];
        xsum = x;
    }
    __syncthreads();
    {   // finalize hv -> bf16 hi/lo in LDS
        int t = tid >> 5, v = tid & 31;
        float x = xsum * invl[t];
        unsigned short hb = f2bf(x);
        hvB_hi[t][v] = hb;
        hvB_lo[t][v] = f2bf(x - bf2f(hb));
    }
    __syncthreads();

    // ================= Phase 3: out = hv @ Wpi^T + bpi =======================
    short8 gh = *(const short8*)&hvB_hi[m][q * 8];
    short8 gl = *(const short8*)&hvB_lo[m][q * 8];
    #pragma unroll
    for (int dt = 0; dt < 8; ++dt) {
        int dbase = w * 128 + dt * 16;
        short8 Ah = *(const short8*)(Wpi_hi + (size_t)(dbase + m) * VDIM + q * 8);
        short8 Al = *(const short8*)(Wpi_lo + (size_t)(dbase + m) * VDIM + q * 8);
        f32x4 o = MFMA16(Al, gh, zero4);
        o = MFMA16(Ah, gl, o);
        o = MFMA16(Ah, gh, o);
        float4 bias = *(const float4*)(bpi + dbase + 4 * q);
        // lane(q,m) reg r -> out[token tok0+m][d = dbase+4q+r]
        float4 r0 = make_float4(o[0] + bias.x, o[1] + bias.y,
                                o[2] + bias.z, o[3] + bias.w);
        *(float4*)(out + (size_t)(tok0 + m) * DIM + dbase + 4 * q) = r0;
    }
}

// ---------------------------------------------------------------------------
extern "C" void kernel_launch(void* const* d_in, const int* in_sizes, int n_in,
                              void* d_out, int out_size, void* d_ws, size_t ws_size,
                              hipStream_t stream) {
    const float* h    = (const float*)d_in[0];
    const float* mask = (const float*)d_in[1];
    const float* Wp   = (const float*)d_in[2];
    const float* bp   = (const float*)d_in[3];
    const float* Wpi  = (const float*)d_in[4];
    const float* bpi  = (const float*)d_in[5];
    const float* emb  = (const float*)d_in[6];
    float* out = (float*)d_out;

    unsigned short* W = (unsigned short*)d_ws;
    float* code_out = out + (size_t)NTOK * DIM;
    float* loss_out = code_out + NTOK;

    hipLaunchKernelGGL(k_prep,  dim3(96),  dim3(256), 0, stream, emb, Wp, Wpi, W, loss_out);
    hipLaunchKernelGGL(k_fused, dim3(512), dim3(512), 0, stream, h, mask, W, bp, bpi, out, code_out);
}

// Round 5
// 142.806 us; speedup vs baseline: 1.0854x; 1.0854x over previous
//
#include <hip/hip_runtime.h>
#include <hip/hip_bf16.h>
#include <math.h>

#define NTOK 8192     // B*L
#define DIM  1024     // D
#define VDIM 32       // V
#define KCODES 4096   // K

// hp is pre-scaled by 2*log2(e): score MFMA yields c*s, softmax weight = exp2(c*s) = e^{2s}.
#define SC 2.8853900817779268f

typedef __attribute__((ext_vector_type(8))) short short8;
typedef __attribute__((ext_vector_type(4))) float f32x4;

// MFMA16(A,B,C): D[row 4q+r = A-row][col m = B-row]; A-frag lane(q,m) holds
// A[m][k=q*8+j], B-frag lane(q,m) holds B[n=m][k=q*8+j]. (verified R2-R4)
#define MFMA16(A,B,C) __builtin_amdgcn_mfma_f32_16x16x32_bf16(A, B, C, 0, 0, 0)

__device__ __forceinline__ unsigned short f2bf(float x) {
    unsigned u = __builtin_bit_cast(unsigned, x);
    u += 0x7FFF + ((u >> 16) & 1);              // RTNE (finite inputs only)
    return (unsigned short)(u >> 16);
}
__device__ __forceinline__ float bf2f(unsigned short b) {
    unsigned u = ((unsigned)b) << 16;
    return __builtin_bit_cast(float, u);
}
__device__ __forceinline__ float fexp2(float x) {
#if __has_builtin(__builtin_amdgcn_exp2f)
    return __builtin_amdgcn_exp2f(x);
#else
    return __expf(0.6931471805599453f * x);
#endif
}

struct U4 { unsigned x, y, z, w; };

// split 8 fp32 -> bf16 hi/lo fragments (RTNE; element j of frag = p[j])
__device__ __forceinline__ void split8(const float* p, short8* H, short8* L) {
    unsigned hh[4], ll[4];
    #pragma unroll
    for (int i = 0; i < 4; ++i) {
        unsigned short a = f2bf(p[2 * i]);
        unsigned short b = f2bf(p[2 * i + 1]);
        hh[i] = (unsigned)a | ((unsigned)b << 16);
        unsigned short la = f2bf(p[2 * i] - bf2f(a));
        unsigned short lb = f2bf(p[2 * i + 1] - bf2f(b));
        ll[i] = (unsigned)la | ((unsigned)lb << 16);
    }
    U4 uh = {hh[0], hh[1], hh[2], hh[3]};
    U4 ul = {ll[0], ll[1], ll[2], ll[3]};
    *H = __builtin_bit_cast(short8, uh);
    *L = __builtin_bit_cast(short8, ul);
}

// pack 8 positive fp32 -> bf16 (round-half-up) via v_perm: 8 adds + 4 perms
__device__ __forceinline__ short8 pack8(const float* p) {
    unsigned u[8];
    #pragma unroll
    for (int j = 0; j < 8; ++j) u[j] = __builtin_bit_cast(unsigned, p[j]) + 0x8000u;
    U4 uh;
    uh.x = __builtin_amdgcn_perm(u[1], u[0], 0x07060302);
    uh.y = __builtin_amdgcn_perm(u[3], u[2], 0x07060302);
    uh.z = __builtin_amdgcn_perm(u[5], u[4], 0x07060302);
    uh.w = __builtin_amdgcn_perm(u[7], u[6], 0x07060302);
    return __builtin_bit_cast(short8, uh);
}

// ---------------------------------------------------------------------------
// ws layout: u16 region then f32 region
// ---------------------------------------------------------------------------
#define OFS_E_HI   0          // E  [4096][32]
#define OFS_E_LO   131072
#define OFS_ET_HI  262144     // Et [32][4096] (hi only; PV drops the lo term)
#define OFS_WP_HI  393216     // Wp [32][1024]
#define OFS_WP_LO  425984
#define OFS_WPI_HI 458752     // Wpi [1024][32]
#define OFS_WPI_LO 491520
#define OFS_HP_HI  524288     // hp  [8192][32] (scaled by SC)
#define OFS_HP_LO  786432
#define F32_BASE   1048576    // u16 units -> float* fbase
#define NSPLIT 8
#define FOFS_HVP 0            // [8][8192][32] fp32 partial hv
#define FOFS_LP  2097152      // [8][8192]
#define FOFS_AMP 2162688      // [8][8192]
#define FOFS_AIP 2228224      // [8][8192] (int)

// ---------------------------------------------------------------------------
// k_prep: normalize emb -> E hi/lo + Et hi (coalesced via LDS transpose);
// split Wp/Wpi; vq_loss = 0.
// ---------------------------------------------------------------------------
__global__ __launch_bounds__(256) void k_prep(const float* __restrict__ emb,
                                              const float* __restrict__ Wp,
                                              const float* __restrict__ Wpi,
                                              unsigned short* __restrict__ W,
                                              float* __restrict__ loss_out) {
    __shared__ __align__(16) unsigned short Th[32][72];
    int bid = blockIdx.x, tid = threadIdx.x;
    if (bid < 64) {                       // 64 codes per block
        int cb = bid * 64;
        int c = tid >> 2, s = tid & 3;    // code-local, v-quarter
        const float* src = emb + (size_t)(cb + c) * VDIM + s * 8;
        float4 a = *(const float4*)src;
        float4 b = *(const float4*)(src + 4);
        float ps = a.x*a.x + a.y*a.y + a.z*a.z + a.w*a.w
                 + b.x*b.x + b.y*b.y + b.z*b.z + b.w*b.w;
        ps += __shfl_xor(ps, 1);
        ps += __shfl_xor(ps, 2);
        float inv = 1.0f / sqrtf(ps);
        float vals[8] = {a.x*inv, a.y*inv, a.z*inv, a.w*inv,
                         b.x*inv, b.y*inv, b.z*inv, b.w*inv};
        short8 H, L;
        split8(vals, &H, &L);
        *(short8*)(W + OFS_E_HI + (size_t)(cb + c) * VDIM + s * 8) = H;
        *(short8*)(W + OFS_E_LO + (size_t)(cb + c) * VDIM + s * 8) = L;
        #pragma unroll
        for (int j = 0; j < 8; ++j) Th[s * 8 + j][c] = f2bf(vals[j]);
        __syncthreads();
        int row = tid >> 3, seg = tid & 7;
        *(short8*)(W + OFS_ET_HI + (size_t)row * KCODES + cb + seg * 8) =
            *(const short8*)&Th[row][seg * 8];
        if (bid == 0 && tid == 0) loss_out[0] = 0.0f;
    } else if (bid < 80) {                // Wp split: 16 blocks x 2048
        int i0 = (bid - 64) * 2048 + tid * 8;
        float4 a = *(const float4*)(Wp + i0);
        float4 b = *(const float4*)(Wp + i0 + 4);
        float vals[8] = {a.x, a.y, a.z, a.w, b.x, b.y, b.z, b.w};
        short8 H, L;
        split8(vals, &H, &L);
        *(short8*)(W + OFS_WP_HI + i0) = H;
        *(short8*)(W + OFS_WP_LO + i0) = L;
    } else {                              // Wpi split: 16 blocks x 2048
        int i0 = (bid - 80) * 2048 + tid * 8;
        float4 a = *(const float4*)(Wpi + i0);
        float4 b = *(const float4*)(Wpi + i0 + 4);
        float vals[8] = {a.x, a.y, a.z, a.w, b.x, b.y, b.z, b.w};
        short8 H, L;
        split8(vals, &H, &L);
        *(short8*)(W + OFS_WPI_HI + i0) = H;
        *(short8*)(W + OFS_WPI_LO + i0) = L;
    }
}

// ---------------------------------------------------------------------------
// k_proj: hp = h @ Wp^T + bp, L2-normalize, scale by SC, write bf16 hi/lo.
// 512 blocks x 256 threads (4 waves); 16 tokens/block; wave = 256-wide k-slice.
// ---------------------------------------------------------------------------
__global__ __launch_bounds__(256) void k_proj(const float* __restrict__ h,
                                              const unsigned short* __restrict__ W,
                                              const float* __restrict__ bp,
                                              unsigned short* __restrict__ hp_hi,
                                              unsigned short* __restrict__ hp_lo) {
    __shared__ __align__(16) float red[4][16][36];
    const unsigned short* Wp_hi = W + OFS_WP_HI;
    const unsigned short* Wp_lo = W + OFS_WP_LO;
    int tid = threadIdx.x;
    int w = tid >> 6, l = tid & 63, q = l >> 4, m = l & 15;
    int tok0 = blockIdx.x * 16;
    const f32x4 zero4 = {0.f, 0.f, 0.f, 0.f};
    f32x4 acc0 = zero4, acc1 = zero4;
    const float* hb = h + (size_t)(tok0 + m) * DIM + w * 256 + q * 8;
    const unsigned short* w0h = Wp_hi + (size_t)m * DIM + w * 256 + q * 8;
    const unsigned short* w0l = Wp_lo + (size_t)m * DIM + w * 256 + q * 8;
    const unsigned short* w1h = w0h + (size_t)16 * DIM;
    const unsigned short* w1l = w0l + (size_t)16 * DIM;
    #pragma unroll
    for (int c = 0; c < 8; ++c) {
        float4 a = *(const float4*)(hb + c * 32);
        float4 b = *(const float4*)(hb + c * 32 + 4);
        float va[8] = {a.x, a.y, a.z, a.w, b.x, b.y, b.z, b.w};
        short8 Bh, Bl;
        split8(va, &Bh, &Bl);
        short8 A0h = *(const short8*)(w0h + c * 32);
        short8 A0l = *(const short8*)(w0l + c * 32);
        short8 A1h = *(const short8*)(w1h + c * 32);
        short8 A1l = *(const short8*)(w1l + c * 32);
        acc0 = MFMA16(A0l, Bl, acc0); acc0 = MFMA16(A0l, Bh, acc0);
        acc0 = MFMA16(A0h, Bl, acc0); acc0 = MFMA16(A0h, Bh, acc0);
        acc1 = MFMA16(A1l, Bl, acc1); acc1 = MFMA16(A1l, Bh, acc1);
        acc1 = MFMA16(A1h, Bl, acc1); acc1 = MFMA16(A1h, Bh, acc1);
    }
    *(f32x4*)&red[w][m][4 * q]      = acc0;   // v = 4q+r, token m
    *(f32x4*)&red[w][m][16 + 4 * q] = acc1;
    __syncthreads();
    #pragma unroll
    for (int half = 0; half < 2; ++half) {
        int t = (tid >> 5) + half * 8, v = tid & 31;
        float s = bp[v];
        #pragma unroll
        for (int j = 0; j < 4; ++j) s += red[j][t][v];
        float sq = s * s;
        #pragma unroll
        for (int off = 1; off < 32; off <<= 1) sq += __shfl_xor(sq, off);
        float nv = s * (SC / sqrtf(sq));
        unsigned short hb2 = f2bf(nv);
        size_t idx = (size_t)(tok0 + t) * VDIM + v;
        hp_hi[idx] = hb2;
        hp_lo[idx] = f2bf(nv - bf2f(hb2));
    }
}

// ---------------------------------------------------------------------------
// k_vq: scores (4-product split fp32) -> exp2 -> argmax -> P@E^T (hi-only) ->
// per-block partials. 1024 blocks x 256 threads (4 waves); block = 64 tokens
// (4 tiles) x 512 codes (wave = 128 codes, 4 chunks of 32). sigma-permuted
// A-rows keep the softmax->PV handoff fully in-register.
// ---------------------------------------------------------------------------
__global__ __launch_bounds__(256, 4) void k_vq(const unsigned short* __restrict__ W,
                                               float* __restrict__ hvp,
                                               float* __restrict__ lp,
                                               float* __restrict__ amp,
                                               int* __restrict__ aip) {
    __shared__ __align__(16) float red2[2][64][36];      // 18.4 KB
    __shared__ float lred[4][4][16];
    __shared__ float amred[4][4][16];
    __shared__ int   aired[4][4][16];

    const unsigned short* E_hi  = W + OFS_E_HI;
    const unsigned short* E_lo  = W + OFS_E_LO;
    const unsigned short* Et_hi = W + OFS_ET_HI;
    const unsigned short* hp_hi = W + OFS_HP_HI;
    const unsigned short* hp_lo = W + OFS_HP_LO;

    int tid = threadIdx.x;
    int w = tid >> 6, l = tid & 63, q = l >> 4, m = l & 15;
    int tg = blockIdx.x >> 3, sp = blockIdx.x & 7;
    int tok0 = tg * 64;
    int cb0 = sp * 512 + w * 128;
    int sig = ((m & 12) << 1) | (m & 3);     // sigma(m) = 8*(m>>2)+(m&3)
    const f32x4 zero4 = {0.f, 0.f, 0.f, 0.f};

    short8 hph[4], hpl[4];
    #pragma unroll
    for (int t = 0; t < 4; ++t) {
        size_t hidx = (size_t)(tok0 + t * 16 + m) * VDIM + q * 8;
        hph[t] = *(const short8*)(hp_hi + hidx);
        hpl[t] = *(const short8*)(hp_lo + hidx);
    }

    f32x4 hv[4][2];
    #pragma unroll
    for (int t = 0; t < 4; ++t) { hv[t][0] = zero4; hv[t][1] = zero4; }
    float ls[4] = {0.f, 0.f, 0.f, 0.f};
    float am[4] = {-1e30f, -1e30f, -1e30f, -1e30f};
    int   ai[4] = {0, 0, 0, 0};

    #pragma unroll 1
    for (int c = 0; c < 4; ++c) {
        int cbase = cb0 + c * 32;
        size_t e0 = (size_t)(cbase + sig) * VDIM + q * 8;
        short8 E0h = *(const short8*)(E_hi + e0);
        short8 E0l = *(const short8*)(E_lo + e0);
        short8 E1h = *(const short8*)(E_hi + e0 + 4 * VDIM);
        short8 E1l = *(const short8*)(E_lo + e0 + 4 * VDIM);
        size_t t0 = (size_t)sig * KCODES + cbase + q * 8;
        short8 T0h = *(const short8*)(Et_hi + t0);
        short8 T1h = *(const short8*)(Et_hi + t0 + (size_t)4 * KCODES);
        int lbase = cbase + 8 * q;
        #pragma unroll
        for (int t = 0; t < 4; ++t) {
            f32x4 s0 = MFMA16(E0l, hpl[t], zero4);
            s0 = MFMA16(E0l, hph[t], s0);
            s0 = MFMA16(E0h, hpl[t], s0);
            s0 = MFMA16(E0h, hph[t], s0);
            f32x4 s1 = MFMA16(E1l, hpl[t], zero4);
            s1 = MFMA16(E1l, hph[t], s1);
            s1 = MFMA16(E1h, hpl[t], s1);
            s1 = MFMA16(E1h, hph[t], s1);
            float p[8];
            #pragma unroll
            for (int r = 0; r < 4; ++r) {
                float sv = s0[r];
                if (sv > am[t]) { am[t] = sv; ai[t] = lbase + r; }
                p[r] = fexp2(sv);
                sv = s1[r];
                if (sv > am[t]) { am[t] = sv; ai[t] = lbase + 4 + r; }
                p[4 + r] = fexp2(sv);
            }
            ls[t] += ((p[0] + p[1]) + (p[2] + p[3])) + ((p[4] + p[5]) + (p[6] + p[7]));
            short8 Ph = pack8(p);
            hv[t][0] = MFMA16(T0h, Ph, hv[t][0]);
            hv[t][1] = MFMA16(T1h, Ph, hv[t][1]);
        }
    }

    // cross-q reduce (lane bits 4,5 share token column m)
    #pragma unroll
    for (int t = 0; t < 4; ++t) {
        #pragma unroll
        for (int off = 16; off <= 32; off <<= 1) {
            ls[t] += __shfl_xor(ls[t], off);
            float a2 = __shfl_xor(am[t], off);
            int   i2 = __shfl_xor(ai[t], off);
            if (a2 > am[t] || (a2 == am[t] && i2 < ai[t])) { am[t] = a2; ai[t] = i2; }
        }
    }
    if (q == 0) {
        #pragma unroll
        for (int t = 0; t < 4; ++t) {
            lred[w][t][m] = ls[t]; amred[w][t][m] = am[t]; aired[w][t][m] = ai[t];
        }
    }
    // hv partials: lane(q,m) reg r -> v = 8q+r (vt0) / 8q+4+r (vt1), token t*16+m
    if (w < 2) {
        #pragma unroll
        for (int t = 0; t < 4; ++t) {
            *(f32x4*)&red2[w][t * 16 + m][8 * q]     = hv[t][0];
            *(f32x4*)&red2[w][t * 16 + m][8 * q + 4] = hv[t][1];
        }
    }
    __syncthreads();
    if (w >= 2) {
        #pragma unroll
        for (int t = 0; t < 4; ++t) {
            f32x4* d0 = (f32x4*)&red2[w - 2][t * 16 + m][8 * q];
            f32x4* d1 = (f32x4*)&red2[w - 2][t * 16 + m][8 * q + 4];
            *d0 = *d0 + hv[t][0];
            *d1 = *d1 + hv[t][1];
        }
    }
    __syncthreads();
    if (tid < 64) {
        int t = tid >> 4, tl = tid & 15;
        float L = 0.f, A = -1e30f;
        int I = 0x7fffffff;
        #pragma unroll
        for (int ww = 0; ww < 4; ++ww) {
            L += lred[ww][t][tl];
            float a2 = amred[ww][t][tl];
            int   i2 = aired[ww][t][tl];
            if (a2 > A || (a2 == A && i2 < I)) { A = a2; I = i2; }
        }
        size_t gi = (size_t)sp * NTOK + tok0 + tid;
        lp[gi] = L; amp[gi] = A; aip[gi] = I;
    }
    #pragma unroll
    for (int it = 0; it < 2; ++it) {
        int idx = it * 256 + tid;
        int tl = idx >> 3, v0 = (idx & 7) * 4;
        f32x4 xs = *(const f32x4*)&red2[0][tl][v0];
        f32x4 ys = *(const f32x4*)&red2[1][tl][v0];
        f32x4 sum = xs + ys;
        *(f32x4*)(hvp + ((size_t)sp * NTOK + tok0 + tl) * VDIM + v0) = sum;
    }
}

// ---------------------------------------------------------------------------
// k_out: merge 8 partial splits -> softmax-normalize hv -> out = hv@Wpi^T+bpi.
// 512 blocks x 256 threads; 16 tokens/block.
// ---------------------------------------------------------------------------
__global__ __launch_bounds__(256) void k_out(const unsigned short* __restrict__ W,
                                             const float* __restrict__ mask,
                                             const float* __restrict__ bpi,
                                             const float* __restrict__ hvp,
                                             const float* __restrict__ lp,
                                             const float* __restrict__ amp,
                                             const int* __restrict__ aip,
                                             float* __restrict__ out,
                                             float* __restrict__ code_out) {
    __shared__ float invl[16];
    __shared__ __align__(16) unsigned short hvh[16][40];
    __shared__ __align__(16) unsigned short hvl[16][40];
    const unsigned short* Wpi_hi = W + OFS_WPI_HI;
    const unsigned short* Wpi_lo = W + OFS_WPI_LO;
    int tid = threadIdx.x;
    int tok0 = blockIdx.x * 16;
    const f32x4 zero4 = {0.f, 0.f, 0.f, 0.f};

    if (tid < 16) {
        int tk = tok0 + tid;
        float L = 0.f, A = -1e30f;
        int I = 0x7fffffff;
        #pragma unroll
        for (int sp = 0; sp < NSPLIT; ++sp) {
            size_t gi = (size_t)sp * NTOK + tk;
            L += lp[gi];
            float a2 = amp[gi];
            int   i2 = aip[gi];
            if (a2 > A || (a2 == A && i2 < I)) { A = a2; I = i2; }
        }
        bool on = (mask[tk] == 1.0f);
        code_out[tk] = on ? (float)I : 0.0f;
        invl[tid] = on ? (1.0f / L) : 0.0f;
    }
    __syncthreads();
    #pragma unroll
    for (int it = 0; it < 2; ++it) {
        int idx = it * 256 + tid;
        int t = idx >> 5, v = idx & 31;
        float x = 0.f;
        #pragma unroll
        for (int sp = 0; sp < NSPLIT; ++sp)
            x += hvp[((size_t)sp * NTOK + tok0 + t) * VDIM + v];
        x *= invl[t];
        unsigned short hb = f2bf(x);
        hvh[t][v] = hb;
        hvl[t][v] = f2bf(x - bf2f(hb));
    }
    __syncthreads();
    int w = tid >> 6, l = tid & 63, q = l >> 4, m = l & 15;
    short8 gh = *(const short8*)&hvh[m][q * 8];
    short8 gl = *(const short8*)&hvl[m][q * 8];
    #pragma unroll
    for (int dt = 0; dt < 16; ++dt) {
        int dbase = w * 256 + dt * 16;
        short8 Ah = *(const short8*)(Wpi_hi + (size_t)(dbase + m) * VDIM + q * 8);
        short8 Al = *(const short8*)(Wpi_lo + (size_t)(dbase + m) * VDIM + q * 8);
        f32x4 o = MFMA16(Al, gh, zero4);
        o = MFMA16(Ah, gl, o);
        o = MFMA16(Ah, gh, o);
        float4 bias = *(const float4*)(bpi + dbase + 4 * q);
        float4 r0 = make_float4(o[0] + bias.x, o[1] + bias.y,
                                o[2] + bias.z, o[3] + bias.w);
        *(float4*)(out + (size_t)(tok0 + m) * DIM + dbase + 4 * q) = r0;
    }
}

// ---------------------------------------------------------------------------
extern "C" void kernel_launch(void* const* d_in, const int* in_sizes, int n_in,
                              void* d_out, int out_size, void* d_ws, size_t ws_size,
                              hipStream_t stream) {
    const float* h    = (const float*)d_in[0];
    const float* mask = (const float*)d_in[1];
    const float* Wp   = (const float*)d_in[2];
    const float* bp   = (const float*)d_in[3];
    const float* Wpi  = (const float*)d_in[4];
    const float* bpi  = (const float*)d_in[5];
    const float* emb  = (const float*)d_in[6];
    float* out = (float*)d_out;

    unsigned short* W = (unsigned short*)d_ws;
    unsigned short* hp_hi = W + OFS_HP_HI;
    unsigned short* hp_lo = W + OFS_HP_LO;
    float* fbase = (float*)(W + F32_BASE);
    float* hvp = fbase + FOFS_HVP;
    float* lpp = fbase + FOFS_LP;
    float* ampp = fbase + FOFS_AMP;
    int*   aipp = (int*)(fbase + FOFS_AIP);

    float* code_out = out + (size_t)NTOK * DIM;
    float* loss_out = code_out + NTOK;

    hipLaunchKernelGGL(k_prep, dim3(96),   dim3(256), 0, stream, emb, Wp, Wpi, W, loss_out);
    hipLaunchKernelGGL(k_proj, dim3(512),  dim3(256), 0, stream, h, W, bp, hp_hi, hp_lo);
    hipLaunchKernelGGL(k_vq,   dim3(1024), dim3(256), 0, stream, W, hvp, lpp, ampp, aipp);
    hipLaunchKernelGGL(k_out,  dim3(512),  dim3(256), 0, stream, W, mask, bpi, hvp, lpp, ampp, aipp, out, code_out);
}